// Round 5
// baseline (23.683 us; speedup 1.0000x reference)
//
#include <hip/hip_runtime.h>

#define NH 64
#define LFULL 2048
#define MH 1024
#define PI_F 3.14159265358979323846f
#define ANG_HALF 1.5339807878856412e-3f   // pi/2048

typedef __attribute__((ext_vector_type(2))) float f32x2;

// ---------------- Prep kernel: per-(head,pole) quadratic coefficients ----------------
// Pair term: v/(z-w) + conj(v)/(z-conj(w)) = [P1 + i*P0*y] / [(m2 - y^2) + i*(na2*y)]
// with z = i*y, w = a+ib (= w*dt), na2 = -2a, m2 = a^2+b^2,
// P0 = 2*vr, P1 = -2*(vr*a + vi*b). All v pre-scaled by dt.
__global__ __launch_bounds__(64) void hippo_prep(
    const float* __restrict__ w_ri,
    const float* __restrict__ P_ri,
    const float* __restrict__ B_ri,
    const float* __restrict__ C_ri,
    const float* __restrict__ log_dt,
    float* __restrict__ poles,     // [256][64][12]
    float* __restrict__ sums)      // [256]
{
    const int h = blockIdx.x;
    const int n = threadIdx.x;
    const float dt = __expf(log_dt[h]);
    const float2 w = ((const float2*)w_ri)[h*NH + n];
    const float2 P = ((const float2*)P_ri)[h*NH + n];
    const float2 B = ((const float2*)B_ri)[h*NH + n];
    const float2 C = ((const float2*)C_ri)[h*NH + n];
    const float a = w.x * dt, b = w.y * dt;
    const float v00r = (B.x*C.x - B.y*C.y) * dt;
    const float v00i = (B.x*C.y + B.y*C.x) * dt;
    const float v01r = (B.x*P.x + B.y*P.y) * dt;   // B*conj(P)
    const float v01i = (B.y*P.x - B.x*P.y) * dt;
    const float v10r = (P.x*C.x - P.y*C.y) * dt;   // P*C
    const float v10i = (P.x*C.y + P.y*C.x) * dt;
    const float v11  = (P.x*P.x + P.y*P.y) * dt;   // |P|^2 (real)
    float* pp = poles + (h*NH + n)*12;
    pp[0]  = -2.f*a;                         // na2
    pp[1]  = fmaf(a, a, b*b);                // m2
    pp[2]  = 2.f*v00r;                       // P0_00
    pp[3]  = -2.f*fmaf(v00r, a, v00i*b);     // P1_00
    pp[4]  = 2.f*v01r;
    pp[5]  = -2.f*fmaf(v01r, a, v01i*b);
    pp[6]  = 2.f*v10r;
    pp[7]  = -2.f*fmaf(v10r, a, v10i*b);
    pp[8]  = 2.f*v11;
    pp[9]  = -2.f*v11*a;                     // v11 imag = 0
    pp[10] = 0.f; pp[11] = 0.f;
    // Nyquist bin (z->inf limit): Re(sum v00)
    float s = v00r;
    #pragma unroll
    for (int off = 32; off > 0; off >>= 1) s += __shfl_down(s, off, 64);
    if (n == 0) sums[h] = s;
}

// ---------------- Main kernel: Cauchy (packed pair) + irfft ----------------
__global__ __launch_bounds__(512) void hippo_ssk(
    const float* __restrict__ poles,
    const float* __restrict__ sums,
    float* __restrict__ out)
{
    __shared__ float2 Kf[MH + 1];    // half-spectrum k_f
    __shared__ float2 bufA[MH];      // FFT ping
    __shared__ float2 bufB[MH];      // FFT pong

    const int h   = blockIdx.x;
    const int tid = threadIdx.x;

    // ---------------- Stage 2: Cauchy kernel, freqs (tid, tid+512) packed ----------------
    {
        const int lA = tid;
        const int lB = tid + 512;
        float sA, cA, sB, cB;
        sincosf(ANG_HALF * (float)lA, &sA, &cA);   // precise: tan blows up near l=1024
        sincosf(ANG_HALF * (float)lB, &sB, &cB);
        f32x2 y;  y.x = 2.f*sA/cA;  y.y = 2.f*sB/cB;   // z = i*y
        const f32x2 y2 = y*y;
        f32x2 A00r = 0.f, A00i = 0.f, A01r = 0.f, A01i = 0.f;
        f32x2 A10r = 0.f, A10i = 0.f, A11r = 0.f, A11i = 0.f;
        const float* pw = poles + h*(NH*12);
        #pragma unroll 4
        for (int n = 0; n < NH; ++n) {
            const float4 q0 = *reinterpret_cast<const float4*>(pw + n*12);
            const float4 q1 = *reinterpret_cast<const float4*>(pw + n*12 + 4);
            const float2 q2 = *reinterpret_cast<const float2*>(pw + n*12 + 8);
            const f32x2 dr  = q0.y - y2;             // m2 - y^2
            const f32x2 di  = q0.x * y;              // na2 * y
            const f32x2 den = dr*dr + di*di;
            f32x2 inv;
            inv.x = __builtin_amdgcn_rcpf(den.x);
            inv.y = __builtin_amdgcn_rcpf(den.y);
            {   const f32x2 ni = q0.z*y;
                const f32x2 rr = q0.w*dr + ni*di;
                const f32x2 ii = ni*dr - q0.w*di;
                A00r += rr*inv;  A00i += ii*inv; }
            {   const f32x2 ni = q1.x*y;
                const f32x2 rr = q1.y*dr + ni*di;
                const f32x2 ii = ni*dr - q1.y*di;
                A01r += rr*inv;  A01i += ii*inv; }
            {   const f32x2 ni = q1.z*y;
                const f32x2 rr = q1.w*dr + ni*di;
                const f32x2 ii = ni*dr - q1.w*di;
                A10r += rr*inv;  A10i += ii*inv; }
            {   const f32x2 ni = q2.x*y;
                const f32x2 rr = q2.y*dr + ni*di;
                const f32x2 ii = ni*dr - q2.y*di;
                A11r += rr*inv;  A11i += ii*inv; }
        }
        // Woodbury: k0 = r00 - r01*r10/(1+r11), packed over both freqs
        const f32x2 nr  = A01r*A10r - A01i*A10i;
        const f32x2 nim = A01r*A10i + A01i*A10r;
        const f32x2 dnr = 1.f + A11r;
        const f32x2 dni = A11i;
        const f32x2 id2 = 1.0f / (dnr*dnr + dni*dni);
        const f32x2 cr  = (nr*dnr + nim*dni)*id2;
        const f32x2 ci  = (nim*dnr - nr*dni)*id2;
        const f32x2 k0r = A00r - cr;
        const f32x2 k0i = A00i - ci;
        const f32x2 hy  = 0.5f*y;                // * 2/(1+omega) = 1 + i*y/2
        Kf[lA] = make_float2(k0r.x - k0i.x*hy.x, k0i.x + k0r.x*hy.x);
        Kf[lB] = make_float2(k0r.y - k0i.y*hy.y, k0i.y + k0r.y*hy.y);
        if (tid == 0) Kf[MH] = make_float2(sums[h], 0.f);
    }
    __syncthreads();

    // ---------------- Stage 3a: half-spectrum -> Z[k] for complex IFFT ----------------
    // E = (X[k]+conj(X[M-k]))/2, O = e^{+i*pi*k/M}*(X[k]-conj(X[M-k]))/2, Z = E + i*O
    #pragma unroll
    for (int i = 0; i < 2; ++i) {
        const int k = tid + 512*i;
        float2 Xk = Kf[k];
        if (k == 0) Xk.y = 0.f;              // bin-0 imag ignored (halfcomplex semantics)
        float2 Xc = Kf[MH - k];
        Xc.y = -Xc.y;
        const float Er = 0.5f*(Xk.x + Xc.x), Ei = 0.5f*(Xk.y + Xc.y);
        const float Tr = 0.5f*(Xk.x - Xc.x), Ti = 0.5f*(Xk.y - Xc.y);
        const float ang = (PI_F/1024.f) * (float)k;
        float sa, ca;
        __sincosf(ang, &sa, &ca);
        const float Or = ca*Tr - sa*Ti;
        const float Oi = ca*Ti + sa*Tr;
        bufA[k] = make_float2(Er - Oi, Ei + Or);
    }
    __syncthreads();

    // ---------------- Stage 3b: 1024-pt radix-2 Stockham inverse FFT ----------------
    float2* Xb = bufA;
    float2* Yb = bufB;
    int m = 1;
    #pragma unroll
    for (int st = 0; st < 10; ++st) {
        const int jm = tid & ~(m - 1);                 // j*m
        const float ang = (PI_F/512.f) * (float)jm;    // inverse FFT: +angle
        float sw, cw;
        __sincosf(ang, &sw, &cw);
        const float2 c0 = Xb[tid];
        const float2 c1 = Xb[tid + 512];
        const int o0 = tid + jm;
        const float drr = c0.x - c1.x, dii = c0.y - c1.y;
        Yb[o0]     = make_float2(c0.x + c1.x, c0.y + c1.y);
        Yb[o0 + m] = make_float2(cw*drr - sw*dii, cw*dii + sw*drr);
        __syncthreads();
        float2* t = Xb; Xb = Yb; Yb = t;
        m <<= 1;
    }

    // ---------------- Stage 3c: interleave + store: x[2n]=Re z[n], x[2n+1]=Im z[n] ----------------
    const float sc = 1.0f/1024.0f;
    float2* op2 = (float2*)(out + (size_t)h * LFULL);
    const float2 z0 = Xb[tid];
    op2[tid]       = make_float2(z0.x*sc, z0.y*sc);
    const float2 z1 = Xb[tid + 512];
    op2[tid + 512] = make_float2(z1.x*sc, z1.y*sc);
}

extern "C" void kernel_launch(void* const* d_in, const int* in_sizes, int n_in,
                              void* d_out, int out_size, void* d_ws, size_t ws_size,
                              hipStream_t stream) {
    const float* w_ri   = (const float*)d_in[0];
    const float* P_ri   = (const float*)d_in[1];
    const float* B_ri   = (const float*)d_in[2];
    const float* C_ri   = (const float*)d_in[3];
    const float* log_dt = (const float*)d_in[4];
    float* out = (float*)d_out;
    const int Hn = in_sizes[4];   // 256 heads

    float* poles = (float*)d_ws;                    // [H][64][12] floats
    float* sums  = poles + (size_t)Hn * NH * 12;    // [H] floats

    hippo_prep<<<dim3(Hn), dim3(64), 0, stream>>>(w_ri, P_ri, B_ri, C_ri, log_dt,
                                                  poles, sums);
    hippo_ssk<<<dim3(Hn), dim3(512), 0, stream>>>(poles, sums, out);
}

// Round 6
// 23.279 us; speedup vs baseline: 1.0173x; 1.0173x over previous
//
#include <hip/hip_runtime.h>

#define NH 64
#define LFULL 2048
#define MH 1024
#define PI_F 3.14159265358979323846f
#define ANG_HALF 1.5339807878856412e-3f   // pi/2048

__global__ __launch_bounds__(1024) void hippo_ssk(
    const float* __restrict__ w_ri,
    const float* __restrict__ P_ri,
    const float* __restrict__ B_ri,
    const float* __restrict__ C_ri,
    const float* __restrict__ log_dt,
    float* __restrict__ out)
{
    __shared__ float pole[NH][12];   // na2, m2, P0_00, P1_00, P0_01, P1_01, P0_10, P1_10, P0_11, P1_11, pad
    __shared__ float2 Kf[MH + 1];    // half-spectrum k_f
    __shared__ float2 bufA[MH];      // FFT ping
    __shared__ float2 bufB[MH];      // FFT pong

    const int h   = blockIdx.x;
    const int tid = threadIdx.x;

    // ---------------- Stage 1: per-pole quadratic coefficients (wave 0) ----------------
    // pair(v) at z=iy:  [P1 + i*P0*y] / [(m2 - y^2) + i*(na2*y)]
    // na2 = -2a, m2 = a^2+b^2, P0 = 2*vr, P1 = -2*(vr*a + vi*b); all v pre-scaled by dt.
    if (tid < NH) {
        const float dt = __expf(log_dt[h]);
        const float2 w = ((const float2*)w_ri)[h*NH + tid];
        const float2 P = ((const float2*)P_ri)[h*NH + tid];
        const float2 B = ((const float2*)B_ri)[h*NH + tid];
        const float2 C = ((const float2*)C_ri)[h*NH + tid];
        const float a = w.x * dt, b = w.y * dt;
        const float v00r = (B.x*C.x - B.y*C.y) * dt;
        const float v00i = (B.x*C.y + B.y*C.x) * dt;
        const float v01r = (B.x*P.x + B.y*P.y) * dt;   // B*conj(P)
        const float v01i = (B.y*P.x - B.x*P.y) * dt;
        const float v10r = (P.x*C.x - P.y*C.y) * dt;   // P*C
        const float v10i = (P.x*C.y + P.y*C.x) * dt;
        const float v11  = (P.x*P.x + P.y*P.y) * dt;   // |P|^2 (real, imag=0)
        float* pp = pole[tid];
        pp[0]  = -2.f*a;
        pp[1]  = fmaf(a, a, b*b);
        pp[2]  = 2.f*v00r;
        pp[3]  = -2.f*fmaf(v00r, a, v00i*b);
        pp[4]  = 2.f*v01r;
        pp[5]  = -2.f*fmaf(v01r, a, v01i*b);
        pp[6]  = 2.f*v10r;
        pp[7]  = -2.f*fmaf(v10r, a, v10i*b);
        pp[8]  = 2.f*v11;
        pp[9]  = -2.f*v11*a;
        pp[10] = 0.f; pp[11] = 0.f;
        // Nyquist bin (z->inf limit): Re(sum v00)
        float s = v00r;
        #pragma unroll
        for (int off = 32; off > 0; off >>= 1) s += __shfl_down(s, off, 64);
        if (tid == 0) Kf[MH] = make_float2(s, 0.f);
    }
    __syncthreads();

    // ---------------- Stage 2: Cauchy kernel at freq l = tid ----------------
    {
        float sh, ch;
        __sincosf(ANG_HALF * (float)tid, &sh, &ch);
        const float y  = 2.f * sh / ch;          // z = i*y, y = 2*tan(pi*l/2048)
        const float y2 = y * y;
        float r00r=0.f,r00i=0.f,r01r=0.f,r01i=0.f;
        float r10r=0.f,r10i=0.f,r11r=0.f,r11i=0.f;
        #pragma unroll 4
        for (int n = 0; n < NH; ++n) {
            const float4 q0 = *reinterpret_cast<const float4*>(&pole[n][0]);
            const float4 q1 = *reinterpret_cast<const float4*>(&pole[n][4]);
            const float2 q2 = *reinterpret_cast<const float2*>(&pole[n][8]);
            const float dr = q0.y - y2;              // m2 - y^2
            const float di = q0.x * y;               // na2 * y
            const float t  = __builtin_amdgcn_rcpf(fmaf(dr, dr, di*di));
            const float U  = dr * t;
            const float V  = di * t;
            const float W  = y * V;
            const float X  = y * U;
            // pair_re = P1*U + P0*W ; pair_im = P0*X - P1*V
            r00r = fmaf(q0.w, U, fmaf(q0.z, W, r00r));
            r00i = fmaf(q0.z, X, fmaf(-q0.w, V, r00i));
            r01r = fmaf(q1.y, U, fmaf(q1.x, W, r01r));
            r01i = fmaf(q1.x, X, fmaf(-q1.y, V, r01i));
            r10r = fmaf(q1.w, U, fmaf(q1.z, W, r10r));
            r10i = fmaf(q1.z, X, fmaf(-q1.w, V, r10i));
            r11r = fmaf(q2.y, U, fmaf(q2.x, W, r11r));
            r11i = fmaf(q2.x, X, fmaf(-q2.y, V, r11i));
        }
        // Woodbury: k0 = r00 - r01*r10/(1+r11)
        const float nr = r01r*r10r - r01i*r10i;
        const float ni = r01r*r10i + r01i*r10r;
        const float dr = 1.f + r11r, di = r11i;
        const float id2 = 1.f / (dr*dr + di*di);
        const float cr = (nr*dr + ni*di)*id2;
        const float ci = (ni*dr - nr*di)*id2;
        const float k0r = r00r - cr, k0i = r00i - ci;
        // * 2/(1+omega) = 1 + i*y/2
        const float hy = 0.5f*y;
        Kf[tid] = make_float2(k0r - k0i*hy, k0i + k0r*hy);
    }
    __syncthreads();

    // ---------------- Stage 3a: half-spectrum -> Z[k] for complex IFFT ----------------
    // E = (X[k]+conj(X[M-k]))/2, O = e^{+i*pi*k/M}*(X[k]-conj(X[M-k]))/2, Z = E + i*O
    {
        const int k = tid;
        float2 Xk = Kf[k];
        if (k == 0) Xk.y = 0.f;              // bin-0 imag ignored (halfcomplex semantics)
        float2 Xc = Kf[MH - k];
        Xc.y = -Xc.y;
        const float Er = 0.5f*(Xk.x + Xc.x), Ei = 0.5f*(Xk.y + Xc.y);
        const float Tr = 0.5f*(Xk.x - Xc.x), Ti = 0.5f*(Xk.y - Xc.y);
        const float ang = (PI_F/1024.f) * (float)k;
        float sa, ca;
        __sincosf(ang, &sa, &ca);
        const float Or = ca*Tr - sa*Ti;
        const float Oi = ca*Ti + sa*Tr;
        bufA[k] = make_float2(Er - Oi, Ei + Or);
    }
    __syncthreads();

    // ---------------- Stage 3b: 1024-pt radix-2 Stockham inverse FFT ----------------
    // All 1024 threads: each computes ONE output point per stage.
    float2* Xb = bufA;
    float2* Yb = bufB;
    int m = 1;
    #pragma unroll
    for (int st = 0; st < 10; ++st) {
        const int o  = tid;
        const int r  = o & (m - 1);
        const int hi = o & m;                    // 0 -> sum output, else twiddled diff
        const int jm = (o >> 1) & ~(m - 1);      // j*m
        const int ti = jm + r;
        const float2 c0 = Xb[ti];
        const float2 c1 = Xb[ti + 512];
        const float ang = (PI_F/512.f) * (float)jm;   // inverse FFT: +angle
        float sw, cw;
        __sincosf(ang, &sw, &cw);
        const float dr = c0.x - c1.x, di = c0.y - c1.y;
        const float tr = cw*dr - sw*di, tii = cw*di + sw*dr;
        const float2 res = hi ? make_float2(tr, tii)
                              : make_float2(c0.x + c1.x, c0.y + c1.y);
        Yb[o] = res;
        __syncthreads();
        float2* t = Xb; Xb = Yb; Yb = t;
        m <<= 1;
    }

    // ---------------- Stage 3c: interleave + store: x[2n]=Re z[n], x[2n+1]=Im z[n] ----------------
    const float sc = 1.0f/1024.0f;
    float2* op2 = (float2*)(out + (size_t)h * LFULL);
    const float2 z = Xb[tid];
    op2[tid] = make_float2(z.x*sc, z.y*sc);
}

extern "C" void kernel_launch(void* const* d_in, const int* in_sizes, int n_in,
                              void* d_out, int out_size, void* d_ws, size_t ws_size,
                              hipStream_t stream) {
    const float* w_ri   = (const float*)d_in[0];
    const float* P_ri   = (const float*)d_in[1];
    const float* B_ri   = (const float*)d_in[2];
    const float* C_ri   = (const float*)d_in[3];
    const float* log_dt = (const float*)d_in[4];
    float* out = (float*)d_out;
    const int Hn = in_sizes[4];   // 256 heads
    hippo_ssk<<<dim3(Hn), dim3(1024), 0, stream>>>(w_ri, P_ri, B_ri, C_ri, log_dt, out);
}